// Round 1
// baseline (4191.650 us; speedup 1.0000x reference)
//
#include <hip/hip_runtime.h>
#include <cmath>

#define HH 542
#define KH 271
#define NPIX (HH*HH)          // 293764
#define BB 8
#define CC3 3
#define NIMG (BB*CC3)         // 24
#define MROWS (NIMG*HH)       // 13008
#define KSZ 31
#define KRAD 15
#define NF 8
#define FS 3

static __device__ __forceinline__ float2 cmul(float2 a, float2 b) {
    return make_float2(a.x*b.x - a.y*b.y, a.x*b.y + a.y*b.x);
}

// ---------------- tables: tw542[r]=exp(-2pi i r/542); Wf/Wi = 271-pt DFT matrices
__global__ void gen_tables(float2* tw542, float2* Wf, float2* Wi) {
    int idx = blockIdx.x*blockDim.x + threadIdx.x;
    const float PI2 = 6.283185307179586f;
    if (idx < HH) {
        float ang = -PI2*(float)idx/(float)HH;
        float s, c; sincosf(ang, &s, &c);
        tw542[idx] = make_float2(c, s);
    }
    if (idx < KH*KH) {
        int k = idx / KH, v = idx - k*KH;
        int r = (k*v) % KH;
        float ang = -PI2*(float)r/(float)KH;
        float s, c; sincosf(ang, &s, &c);
        Wf[idx] = make_float2(c, s);
        Wi[idx] = make_float2(c, -s);
    }
}

// ---------------- edgetaper alpha vectors (closed-form autocorrelation)
__global__ void alpha_kernel(const float* __restrict__ kk, float* __restrict__ valpha) {
    int b = blockIdx.x;
    int t = threadIdx.x;
    __shared__ float proj[2][KSZ];
    __shared__ float ac[2][KSZ];
    const float* kb = kk + b*KSZ*KSZ;
    if (t < KSZ) {
        float s = 0;
        for (int j = 0; j < KSZ; j++) s += kb[t*KSZ + j];
        proj[0][t] = s;                      // axis-0 (rows): sum over axis 1
    } else if (t >= 32 && t < 32+KSZ) {
        int j = t - 32;
        float s = 0;
        for (int i = 0; i < KSZ; i++) s += kb[i*KSZ + j];
        proj[1][j] = s;                      // axis-1 (cols)
    }
    __syncthreads();
    if (t < KSZ) {
        float s0 = 0, s1 = 0;
        for (int m = 0; m + t < KSZ; m++) {
            s0 += proj[0][m]*proj[0][m+t];
            s1 += proj[1][m]*proj[1][m+t];
        }
        ac[0][t] = s0; ac[1][t] = s1;
    }
    __syncthreads();
    float inv0 = 1.0f/ac[0][0];
    float inv1 = 1.0f/ac[1][0];
    for (int d = t; d < HH; d += blockDim.x) {
        for (int a = 0; a < 2; a++) {
            float z;
            if (d <= 30)                 z = ac[a][d];
            else if (d >= 511 && d <= 540) z = ac[a][541-d];
            else if (d == 541)           z = ac[a][0];
            else                         z = 0.0f;
            valpha[(b*2 + a)*HH + d] = 1.0f - z*(a ? inv1 : inv0);
        }
    }
}

// ---------------- Dk = psf2otf(k) via two small DFT stages
__global__ void dk_stage1(const float* __restrict__ kk, const float2* __restrict__ tw,
                          float2* __restrict__ T1) {
    int idx = blockIdx.x*blockDim.x + threadIdx.x;
    if (idx >= BB*KSZ*HH) return;
    int v  = idx % HH;
    int bm = idx / HH;
    int m  = bm % KSZ;
    int b  = bm / KSZ;
    const float* kb = kk + (b*KSZ + m)*KSZ;
    float2 acc = make_float2(0.f, 0.f);
    for (int n = 0; n < KSZ; n++) {
        int r = (v*(n - KRAD)) % HH;
        if (r < 0) r += HH;
        float2 w = tw[r];
        float kv = kb[n];
        acc.x = fmaf(kv, w.x, acc.x);
        acc.y = fmaf(kv, w.y, acc.y);
    }
    T1[idx] = acc;
}

__global__ void dk_stage2(const float2* __restrict__ T1, const float2* __restrict__ tw,
                          float2* __restrict__ Dk) {
    int idx = blockIdx.x*blockDim.x + threadIdx.x;
    if (idx >= BB*NPIX) return;
    int uv = idx % NPIX;
    int b  = idx / NPIX;
    int u  = uv / HH;
    float2 acc = make_float2(0.f, 0.f);
    int v = uv - u*HH;
    for (int m = 0; m < KSZ; m++) {
        int r = (u*(m - KRAD)) % HH;
        if (r < 0) r += HH;
        float2 w = tw[r];
        float2 t = T1[(b*KSZ + m)*HH + v];
        acc.x += t.x*w.x - t.y*w.y;
        acc.y += t.x*w.y + t.y*w.x;
    }
    Dk[idx] = acc;
}

// ---------------- Dg_sum[c][u][v] = exp(lam)*sum_f |DFT(filt[f,c])|^2
__global__ void dgs_kernel(const float* __restrict__ filt, const float* __restrict__ lamp,
                           const float2* __restrict__ tw, float* __restrict__ Dgs) {
    int uv = blockIdx.x*blockDim.x + threadIdx.x;
    if (uv >= NPIX) return;
    int u = uv / HH;
    int v = uv - u*HH;
    float el = expf(lamp[0]);
    float2 ph[3][3];
    for (int m = 0; m < 3; m++) {
        int ru = (u*(m-1)) % HH; if (ru < 0) ru += HH;
        float2 wu = tw[ru];
        for (int n = 0; n < 3; n++) {
            int rv = (v*(n-1)) % HH; if (rv < 0) rv += HH;
            ph[m][n] = cmul(wu, tw[rv]);
        }
    }
    for (int c = 0; c < CC3; c++) {
        float s = 0.f;
        for (int f = 0; f < NF; f++) {
            float2 acc = make_float2(0.f, 0.f);
            const float* fp = filt + ((f*CC3 + c)*FS)*FS;
            #pragma unroll
            for (int m = 0; m < 3; m++)
                #pragma unroll
                for (int n = 0; n < 3; n++) {
                    float fv = fp[m*3+n];
                    acc.x = fmaf(fv, ph[m][n].x, acc.x);
                    acc.y = fmaf(fv, ph[m][n].y, acc.y);
                }
            s = fmaf(acc.x, acc.x, fmaf(acc.y, acc.y, s));
        }
        Dgs[c*NPIX + uv] = s*el;
    }
}

// ---------------- edge-replicate pad: y[512x512] -> R0/CA [542x542]
__global__ void pad_kernel(const float* __restrict__ y, float* __restrict__ R0,
                           float2* __restrict__ CA) {
    int idx = blockIdx.x*blockDim.x + threadIdx.x;
    if (idx >= NIMG*NPIX) return;
    int ij = idx % NPIX;
    int n  = idx / NPIX;
    int i = ij / HH, j = ij - i*HH;
    int yi = min(max(i - KRAD, 0), 511);
    int yj = min(max(j - KRAD, 0), 511);
    float val = y[((size_t)n*512 + yi)*512 + yj];
    R0[idx] = val;
    CA[idx] = make_float2(val, 0.0f);
}

// ---------------- pointwise: CB = CA * Dk[b]
__global__ void mulotf_kernel(const float2* __restrict__ CA, const float2* __restrict__ Dk,
                              float2* __restrict__ CB) {
    int idx = blockIdx.x*blockDim.x + threadIdx.x;
    if (idx >= NIMG*NPIX) return;
    int uv = idx % NPIX;
    int n  = idx / NPIX;
    int b  = n / CC3;
    CB[idx] = cmul(CA[idx], Dk[b*NPIX + uv]);
}

// ---------------- edgetaper blend: img = a*img + (1-a)*Re(blurred)
__global__ void blend_kernel(const float2* __restrict__ CB, const float* __restrict__ valpha,
                             float* __restrict__ R0, float2* __restrict__ CA) {
    int idx = blockIdx.x*blockDim.x + threadIdx.x;
    if (idx >= NIMG*NPIX) return;
    int uv = idx % NPIX;
    int n  = idx / NPIX;
    int b  = n / CC3;
    int i = uv / HH, j = uv - i*HH;
    float a  = valpha[b*2*HH + i] * valpha[(b*2+1)*HH + j];
    float bl = CB[idx].x;
    float nv = fmaf(a, R0[idx] - bl, bl);   // a*img + (1-a)*bl
    R0[idx] = nv;
    CA[idx] = make_float2(nv, 0.0f);
}

// ---------------- Wiener: CB = CA * conj(Dk) / (|Dk|^2 + Dgs[c])
__global__ void wiener_kernel(const float2* __restrict__ CA, const float2* __restrict__ Dk,
                              const float* __restrict__ Dgs, float2* __restrict__ CB) {
    int idx = blockIdx.x*blockDim.x + threadIdx.x;
    if (idx >= NIMG*NPIX) return;
    int uv = idx % NPIX;
    int n  = idx / NPIX;
    int b  = n / CC3;
    int c  = n - b*CC3;
    float2 dk = Dk[b*NPIX + uv];
    float om = 1.0f/(dk.x*dk.x + dk.y*dk.y + Dgs[c*NPIX + uv]);
    float2 m = make_float2(dk.x*om, -dk.y*om);
    CB[idx] = cmul(CA[idx], m);
}

__global__ void out_kernel(const float2* __restrict__ CB, float* __restrict__ out) {
    int idx = blockIdx.x*blockDim.x + threadIdx.x;
    if (idx >= NIMG*NPIX) return;
    out[idx] = CB[idx].x;
}

// ---------------- batched split-radix DFT pass (rows of 542, even/odd K=271 GEMM),
// writes output TRANSPOSED per image; two passes = fft2. conjtw+scale => inverse.
__global__ void __launch_bounds__(256)
fft_pass(const float2* __restrict__ Ain, float2* __restrict__ Aout,
         const float2* __restrict__ Wm, const float2* __restrict__ tw542,
         float scale, int conjtw, int Mrows)
{
    __shared__ float4 As[64][17];    // [row][k]: (even.re, even.im, odd.re, odd.im)
    __shared__ float2 Ws[16][64];    // [k][v1]
    int tid = threadIdx.x;
    int tx = tid & 15, ty = tid >> 4;
    int r0 = blockIdx.y * 64;
    int v0 = blockIdx.x * 64;

    float2 Ea[4][4], Oa[4][4];
    #pragma unroll
    for (int i = 0; i < 4; i++)
        #pragma unroll
        for (int j = 0; j < 4; j++) {
            Ea[i][j] = make_float2(0.f, 0.f);
            Oa[i][j] = make_float2(0.f, 0.f);
        }

    for (int k0 = 0; k0 < KH; k0 += 16) {
        #pragma unroll
        for (int q = 0; q < 4; q++) {
            int idx = tid + 256*q;
            int row = idx >> 4;
            int kk  = idx & 15;
            int r = r0 + row, k = k0 + kk;
            float4 val = make_float4(0.f, 0.f, 0.f, 0.f);
            if (r < Mrows && k < KH)
                val = *reinterpret_cast<const float4*>(Ain + (size_t)r*HH + 2*k);
            As[row][kk] = val;
        }
        #pragma unroll
        for (int q = 0; q < 4; q++) {
            int idx = tid + 256*q;
            int kkk  = idx >> 6;
            int vloc = idx & 63;
            int k = k0 + kkk, v = v0 + vloc;
            float2 wv = make_float2(0.f, 0.f);
            if (k < KH && v < KH) wv = Wm[k*KH + v];
            Ws[kkk][vloc] = wv;
        }
        __syncthreads();
        #pragma unroll 4
        for (int kk = 0; kk < 16; kk++) {
            float4 a[4]; float2 w[4];
            #pragma unroll
            for (int i = 0; i < 4; i++) a[i] = As[ty*4 + i][kk];
            #pragma unroll
            for (int j = 0; j < 4; j++) w[j] = Ws[kk][tx + 16*j];
            #pragma unroll
            for (int i = 0; i < 4; i++)
                #pragma unroll
                for (int j = 0; j < 4; j++) {
                    Ea[i][j].x = fmaf(a[i].x, w[j].x, fmaf(-a[i].y, w[j].y, Ea[i][j].x));
                    Ea[i][j].y = fmaf(a[i].x, w[j].y, fmaf( a[i].y, w[j].x, Ea[i][j].y));
                    Oa[i][j].x = fmaf(a[i].z, w[j].x, fmaf(-a[i].w, w[j].y, Oa[i][j].x));
                    Oa[i][j].y = fmaf(a[i].z, w[j].y, fmaf( a[i].w, w[j].x, Oa[i][j].y));
                }
        }
        __syncthreads();
    }

    #pragma unroll
    for (int j = 0; j < 4; j++) {
        int v1 = v0 + tx + 16*j;
        if (v1 >= KH) continue;
        float2 t = tw542[v1];
        if (conjtw) t.y = -t.y;
        #pragma unroll
        for (int i = 0; i < 4; i++) {
            int r = r0 + ty*4 + i;
            if (r >= Mrows) continue;
            int img = r / HH;
            int col = r - img*HH;
            float2 E = Ea[i][j], O = Oa[i][j];
            float2 tO = make_float2(t.x*O.x - t.y*O.y, t.x*O.y + t.y*O.x);
            float2 lo = make_float2((E.x + tO.x)*scale, (E.y + tO.y)*scale);
            float2 hi = make_float2((E.x - tO.x)*scale, (E.y - tO.y)*scale);
            float2* outp = Aout + (size_t)img*NPIX;
            outp[(size_t)v1*HH + col]      = lo;
            outp[(size_t)(v1+KH)*HH + col] = hi;
        }
    }
}

extern "C" void kernel_launch(void* const* d_in, const int* in_sizes, int n_in,
                              void* d_out, int out_size, void* d_ws, size_t ws_size,
                              hipStream_t stream) {
    const float* y    = (const float*)d_in[0];
    const float* k    = (const float*)d_in[1];
    const float* lam  = (const float*)d_in[2];
    const float* filt = (const float*)d_in[3];
    float* out = (float*)d_out;

    char* base = (char*)d_ws;
    size_t off = 0;
    auto alloc = [&](size_t bytes) {
        void* p = base + off;
        off = (off + bytes + 511) & ~(size_t)511;
        return p;
    };
    float2* CA   = (float2*)alloc(sizeof(float2)*(size_t)NIMG*NPIX);
    float2* CB   = (float2*)alloc(sizeof(float2)*(size_t)NIMG*NPIX);
    float*  R0   = (float*) alloc(sizeof(float)*(size_t)NIMG*NPIX);
    float2* Dk   = (float2*)alloc(sizeof(float2)*(size_t)BB*NPIX);
    float2* T1   = (float2*)alloc(sizeof(float2)*(size_t)BB*KSZ*HH);
    float*  Dgs  = (float*) alloc(sizeof(float)*(size_t)CC3*NPIX);
    float2* Wf   = (float2*)alloc(sizeof(float2)*(size_t)KH*KH);
    float2* Wi   = (float2*)alloc(sizeof(float2)*(size_t)KH*KH);
    float2* tw   = (float2*)alloc(sizeof(float2)*(size_t)HH);
    float*  valp = (float*) alloc(sizeof(float)*(size_t)BB*2*HH);
    (void)ws_size; (void)in_sizes; (void)n_in; (void)out_size;

    const int TPB = 256;
    auto nb = [](long n) { return (int)((n + 255)/256); };

    gen_tables<<<nb((long)KH*KH), TPB, 0, stream>>>(tw, Wf, Wi);
    alpha_kernel<<<BB, 64, 0, stream>>>(k, valp);
    dk_stage1<<<nb((long)BB*KSZ*HH), TPB, 0, stream>>>(k, tw, T1);
    dk_stage2<<<nb((long)BB*NPIX), TPB, 0, stream>>>(T1, tw, Dk);
    dgs_kernel<<<nb((long)NPIX), TPB, 0, stream>>>(filt, lam, tw, Dgs);
    pad_kernel<<<nb((long)NIMG*NPIX), TPB, 0, stream>>>(y, R0, CA);

    dim3 pg((KH+63)/64, (MROWS+63)/64);
    const float isc = 1.0f/(float)HH;
    // forward fft2 of padded image: CA -> CB -> CA
    fft_pass<<<pg, TPB, 0, stream>>>(CA, CB, Wf, tw, 1.0f, 0, MROWS);
    fft_pass<<<pg, TPB, 0, stream>>>(CB, CA, Wf, tw, 1.0f, 0, MROWS);
    for (int it = 0; it < 3; it++) {
        mulotf_kernel<<<nb((long)NIMG*NPIX), TPB, 0, stream>>>(CA, Dk, CB);
        fft_pass<<<pg, TPB, 0, stream>>>(CB, CA, Wi, tw, isc, 1, MROWS);
        fft_pass<<<pg, TPB, 0, stream>>>(CA, CB, Wi, tw, isc, 1, MROWS);
        blend_kernel<<<nb((long)NIMG*NPIX), TPB, 0, stream>>>(CB, valp, R0, CA);
        fft_pass<<<pg, TPB, 0, stream>>>(CA, CB, Wf, tw, 1.0f, 0, MROWS);
        fft_pass<<<pg, TPB, 0, stream>>>(CB, CA, Wf, tw, 1.0f, 0, MROWS);
    }
    wiener_kernel<<<nb((long)NIMG*NPIX), TPB, 0, stream>>>(CA, Dk, Dgs, CB);
    fft_pass<<<pg, TPB, 0, stream>>>(CB, CA, Wi, tw, isc, 1, MROWS);
    fft_pass<<<pg, TPB, 0, stream>>>(CA, CB, Wi, tw, isc, 1, MROWS);
    out_kernel<<<nb((long)NIMG*NPIX), TPB, 0, stream>>>(CB, out);
}

// Round 2
// 2201.926 us; speedup vs baseline: 1.9036x; 1.9036x over previous
//
#include <hip/hip_runtime.h>
#include <cmath>

#define HH 542
#define KH 271
#define NPIX (HH*HH)          // 293764
#define BB 8
#define CC3 3
#define NCH (BB*CC3)          // 24 real channels
#define NP 12                 // 12 packed complex planes
#define MROWS (NP*HH)         // 6504 rows per pass
#define KSZ 31
#define KRAD 15
#define NF 8
#define FS 3
#define RT 32                 // rows per fft block

static __device__ __forceinline__ float2 cmul(float2 a, float2 b) {
    return make_float2(a.x*b.x - a.y*b.y, a.x*b.y + a.y*b.x);
}

// pair p -> the two real channel indices it packs (.x real side, .y imag side)
static __device__ __forceinline__ void pair_chans(int p, int& n1, int& n2) {
    if (p < 8) { n1 = 3*p;     n2 = 3*p + 1; }       // (b,0)+(b,1)
    else       { int q = p-8; n1 = 6*q + 2; n2 = 6*q + 5; } // (2q,2)+(2q+1,2)
}

// ---------------- tables: tw542[r]=exp(-2pi i r/542); Wf/Wi = 271-pt DFT matrices
__global__ void gen_tables(float2* tw542, float2* Wf, float2* Wi) {
    int idx = blockIdx.x*blockDim.x + threadIdx.x;
    const float PI2 = 6.283185307179586f;
    if (idx < HH) {
        float ang = -PI2*(float)idx/(float)HH;
        float s, c; sincosf(ang, &s, &c);
        tw542[idx] = make_float2(c, s);
    }
    if (idx < KH*KH) {
        int k = idx / KH, v = idx - k*KH;
        int r = (k*v) % KH;
        float ang = -PI2*(float)r/(float)KH;
        float s, c; sincosf(ang, &s, &c);
        Wf[idx] = make_float2(c, s);
        Wi[idx] = make_float2(c, -s);
    }
}

// ---------------- edgetaper alpha vectors (closed-form autocorrelation)
__global__ void alpha_kernel(const float* __restrict__ kk, float* __restrict__ valpha) {
    int b = blockIdx.x;
    int t = threadIdx.x;
    __shared__ float proj[2][KSZ];
    __shared__ float ac[2][KSZ];
    const float* kb = kk + b*KSZ*KSZ;
    if (t < KSZ) {
        float s = 0;
        for (int j = 0; j < KSZ; j++) s += kb[t*KSZ + j];
        proj[0][t] = s;
    } else if (t >= 32 && t < 32+KSZ) {
        int j = t - 32;
        float s = 0;
        for (int i = 0; i < KSZ; i++) s += kb[i*KSZ + j];
        proj[1][j] = s;
    }
    __syncthreads();
    if (t < KSZ) {
        float s0 = 0, s1 = 0;
        for (int m = 0; m + t < KSZ; m++) {
            s0 += proj[0][m]*proj[0][m+t];
            s1 += proj[1][m]*proj[1][m+t];
        }
        ac[0][t] = s0; ac[1][t] = s1;
    }
    __syncthreads();
    float inv0 = 1.0f/ac[0][0];
    float inv1 = 1.0f/ac[1][0];
    for (int d = t; d < HH; d += blockDim.x) {
        for (int a = 0; a < 2; a++) {
            float z;
            if (d <= 30)                   z = ac[a][d];
            else if (d >= 511 && d <= 540) z = ac[a][541-d];
            else if (d == 541)             z = ac[a][0];
            else                           z = 0.0f;
            valpha[(b*2 + a)*HH + d] = 1.0f - z*(a ? inv1 : inv0);
        }
    }
}

// ---------------- Dk = psf2otf(k) via two small DFT stages
__global__ void dk_stage1(const float* __restrict__ kk, const float2* __restrict__ tw,
                          float2* __restrict__ T1) {
    int idx = blockIdx.x*blockDim.x + threadIdx.x;
    if (idx >= BB*KSZ*HH) return;
    int v  = idx % HH;
    int bm = idx / HH;
    int m  = bm % KSZ;
    int b  = bm / KSZ;
    const float* kb = kk + (b*KSZ + m)*KSZ;
    float2 acc = make_float2(0.f, 0.f);
    for (int n = 0; n < KSZ; n++) {
        int r = (v*(n - KRAD)) % HH;
        if (r < 0) r += HH;
        float2 w = tw[r];
        float kv = kb[n];
        acc.x = fmaf(kv, w.x, acc.x);
        acc.y = fmaf(kv, w.y, acc.y);
    }
    T1[idx] = acc;
}

__global__ void dk_stage2(const float2* __restrict__ T1, const float2* __restrict__ tw,
                          float2* __restrict__ Dk) {
    int idx = blockIdx.x*blockDim.x + threadIdx.x;
    if (idx >= BB*NPIX) return;
    int uv = idx % NPIX;
    int b  = idx / NPIX;
    int u  = uv / HH;
    int v  = uv - u*HH;
    float2 acc = make_float2(0.f, 0.f);
    for (int m = 0; m < KSZ; m++) {
        int r = (u*(m - KRAD)) % HH;
        if (r < 0) r += HH;
        float2 w = tw[r];
        float2 t = T1[(b*KSZ + m)*HH + v];
        acc.x += t.x*w.x - t.y*w.y;
        acc.y += t.x*w.y + t.y*w.x;
    }
    Dk[idx] = acc;
}

// ---------------- Dg_sum[c][u][v] = exp(lam)*sum_f |DFT(filt[f,c])|^2
__global__ void dgs_kernel(const float* __restrict__ filt, const float* __restrict__ lamp,
                           const float2* __restrict__ tw, float* __restrict__ Dgs) {
    int uv = blockIdx.x*blockDim.x + threadIdx.x;
    if (uv >= NPIX) return;
    int u = uv / HH;
    int v = uv - u*HH;
    float el = expf(lamp[0]);
    float2 ph[3][3];
    for (int m = 0; m < 3; m++) {
        int ru = (u*(m-1)) % HH; if (ru < 0) ru += HH;
        float2 wu = tw[ru];
        for (int n = 0; n < 3; n++) {
            int rv = (v*(n-1)) % HH; if (rv < 0) rv += HH;
            ph[m][n] = cmul(wu, tw[rv]);
        }
    }
    for (int c = 0; c < CC3; c++) {
        float s = 0.f;
        for (int f = 0; f < NF; f++) {
            float2 acc = make_float2(0.f, 0.f);
            const float* fp = filt + ((f*CC3 + c)*FS)*FS;
            #pragma unroll
            for (int m = 0; m < 3; m++)
                #pragma unroll
                for (int n = 0; n < 3; n++) {
                    float fv = fp[m*3+n];
                    acc.x = fmaf(fv, ph[m][n].x, acc.x);
                    acc.y = fmaf(fv, ph[m][n].y, acc.y);
                }
            s = fmaf(acc.x, acc.x, fmaf(acc.y, acc.y, s));
        }
        Dgs[c*NPIX + uv] = s*el;
    }
}

// ---------------- edge-replicate pad + pack pairs: y[24][512²] -> R0[24][542²], CA[12][542²]
__global__ void pad_pack(const float* __restrict__ y, float* __restrict__ R0,
                         float2* __restrict__ CA) {
    int idx = blockIdx.x*blockDim.x + threadIdx.x;
    if (idx >= NP*NPIX) return;
    int uv = idx % NPIX;
    int p  = idx / NPIX;
    int n1, n2; pair_chans(p, n1, n2);
    int i = uv / HH, j = uv - i*HH;
    int yi = min(max(i - KRAD, 0), 511);
    int yj = min(max(j - KRAD, 0), 511);
    int yo = yi*512 + yj;
    float v1 = y[(size_t)n1*262144 + yo];
    float v2 = y[(size_t)n2*262144 + yo];
    R0[(size_t)n1*NPIX + uv] = v1;
    R0[(size_t)n2*NPIX + uv] = v2;
    CA[idx] = make_float2(v1, v2);
}

// ---------------- Hermitian unpack, per-channel multiply, repack.
// mode 0: M = Dk[b]   mode 1: M = conj(Dk[b]) / (|Dk[b]|^2 + Dgs[c])
__global__ void specmul(const float2* __restrict__ CA, const float2* __restrict__ Dk,
                        const float* __restrict__ Dgs, float2* __restrict__ CB, int mode) {
    int idx = blockIdx.x*blockDim.x + threadIdx.x;
    if (idx >= NP*NPIX) return;
    int uv = idx % NPIX;
    int p  = idx / NPIX;
    int n1, n2; pair_chans(p, n1, n2);
    int b1 = n1/3, c1 = n1 - 3*b1;
    int b2 = n2/3, c2 = n2 - 3*b2;
    int i = uv / HH, j = uv - i*HH;
    int ni = i ? HH - i : 0;
    int nj = j ? HH - j : 0;
    float2 Z  = CA[(size_t)p*NPIX + uv];
    float2 Zm = CA[(size_t)p*NPIX + ni*HH + nj];
    float2 F1 = make_float2(0.5f*(Z.x + Zm.x), 0.5f*(Z.y - Zm.y));
    float2 F2 = make_float2(0.5f*(Z.y + Zm.y), 0.5f*(Zm.x - Z.x));
    float2 d1 = Dk[(size_t)b1*NPIX + uv];
    float2 d2 = Dk[(size_t)b2*NPIX + uv];
    float2 M1, M2;
    if (mode == 0) {
        M1 = d1; M2 = d2;
    } else {
        float o1 = 1.0f/(d1.x*d1.x + d1.y*d1.y + Dgs[(size_t)c1*NPIX + uv]);
        float o2 = 1.0f/(d2.x*d2.x + d2.y*d2.y + Dgs[(size_t)c2*NPIX + uv]);
        M1 = make_float2(d1.x*o1, -d1.y*o1);
        M2 = make_float2(d2.x*o2, -d2.y*o2);
    }
    float2 W1 = cmul(M1, F1);
    float2 W2 = cmul(M2, F2);
    CB[idx] = make_float2(W1.x - W2.y, W1.y + W2.x);
}

// ---------------- edgetaper blend: img_s = a_s*img_s + (1-a_s)*blur_s; repack
__global__ void blend_kernel(const float2* __restrict__ CB, const float* __restrict__ valpha,
                             float* __restrict__ R0, float2* __restrict__ CA) {
    int idx = blockIdx.x*blockDim.x + threadIdx.x;
    if (idx >= NP*NPIX) return;
    int uv = idx % NPIX;
    int p  = idx / NPIX;
    int n1, n2; pair_chans(p, n1, n2);
    int b1 = n1/3, b2 = n2/3;
    int i = uv / HH, j = uv - i*HH;
    float2 bl = CB[idx];
    float a1 = valpha[b1*2*HH + i] * valpha[(b1*2+1)*HH + j];
    float a2 = valpha[b2*2*HH + i] * valpha[(b2*2+1)*HH + j];
    float o1 = R0[(size_t)n1*NPIX + uv];
    float o2 = R0[(size_t)n2*NPIX + uv];
    float v1 = fmaf(a1, o1 - bl.x, bl.x);
    float v2 = fmaf(a2, o2 - bl.y, bl.y);
    R0[(size_t)n1*NPIX + uv] = v1;
    R0[(size_t)n2*NPIX + uv] = v2;
    CA[idx] = make_float2(v1, v2);
}

// ---------------- unpack final: out[n1]=Re, out[n2]=Im
__global__ void out_kernel(const float2* __restrict__ CB, float* __restrict__ out) {
    int idx = blockIdx.x*blockDim.x + threadIdx.x;
    if (idx >= NP*NPIX) return;
    int uv = idx % NPIX;
    int p  = idx / NPIX;
    int n1, n2; pair_chans(p, n1, n2);
    float2 v = CB[idx];
    out[(size_t)n1*NPIX + uv] = v.x;
    out[(size_t)n2*NPIX + uv] = v.y;
}

// ---------------- batched split DFT pass (rows of 542 = even/odd K=271 GEMM),
// writes transposed; two passes = fft2. conjtw+scale => inverse.
// 32 rows x 64 v1-cols per block, 256 threads, 2x4 (E,O) per thread,
// software-pipelined global->reg->LDS staging.
__global__ void __launch_bounds__(256)
fft_pass(const float2* __restrict__ Ain, float2* __restrict__ Aout,
         const float2* __restrict__ Wm, const float2* __restrict__ tw542,
         float scale, int conjtw, int Mrows)
{
    __shared__ float4 As[RT][17];    // [row][k]: (even.re, even.im, odd.re, odd.im)
    __shared__ float2 Ws[16][64];    // [k][v1]
    int tid = threadIdx.x;
    int tx = tid & 15, ty = tid >> 4;
    int r0 = blockIdx.y * RT;
    int v0 = blockIdx.x * 64;

    // staging roles
    int arow = tid >> 4;   // 0..15 (q adds 16)
    int akk  = tid & 15;
    int wk   = tid >> 6;   // 0..3 (q adds 4)
    int wv   = tid & 63;

    // A base pointers (float4 index k): Ain + r*HH float2 = k-th float4 at +k
    const float4* pA[2];
    bool rv[2];
    #pragma unroll
    for (int q = 0; q < 2; q++) {
        int r = r0 + arow + 16*q;
        rv[q] = (r < Mrows);
        int rc = rv[q] ? r : 0;
        pA[q] = reinterpret_cast<const float4*>(Ain + (size_t)rc*HH) + akk;
    }
    bool wvalid = (v0 + wv) < KH;
    const float2* pW = Wm + wk*KH + (wvalid ? (v0 + wv) : 0);

    float2 E[2][4], O[2][4];
    #pragma unroll
    for (int i = 0; i < 2; i++)
        #pragma unroll
        for (int j = 0; j < 4; j++) {
            E[i][j] = make_float2(0.f, 0.f);
            O[i][j] = make_float2(0.f, 0.f);
        }

    float4 regA[2];
    float2 regW[4];
    // prologue: load tile 0
    #pragma unroll
    for (int q = 0; q < 2; q++) {
        int k = akk;  // k0=0
        regA[q] = (rv[q] && k < KH) ? pA[q][0] : make_float4(0,0,0,0);
    }
    #pragma unroll
    for (int q = 0; q < 4; q++) {
        int k = wk + 4*q;
        regW[q] = (wvalid && k < KH) ? pW[(size_t)(4*q)*KH] : make_float2(0,0);
    }

    for (int k0 = 0; k0 < KH; k0 += 16) {
        As[arow][akk]      = regA[0];
        As[arow+16][akk]   = regA[1];
        Ws[wk][wv]         = regW[0];
        Ws[wk+4][wv]       = regW[1];
        Ws[wk+8][wv]       = regW[2];
        Ws[wk+12][wv]      = regW[3];
        __syncthreads();

        int kn = k0 + 16;
        if (kn < KH) {
            #pragma unroll
            for (int q = 0; q < 2; q++) {
                int k = kn + akk;
                regA[q] = (rv[q] && k < KH) ? pA[q][kn] : make_float4(0,0,0,0);
            }
            #pragma unroll
            for (int q = 0; q < 4; q++) {
                int k = kn + wk + 4*q;
                regW[q] = (wvalid && k < KH) ? pW[(size_t)(kn + 4*q)*KH] : make_float2(0,0);
            }
        }

        #pragma unroll 4
        for (int kk = 0; kk < 16; kk++) {
            float4 a[2]; float2 w[4];
            #pragma unroll
            for (int i = 0; i < 2; i++) a[i] = As[ty*2 + i][kk];
            #pragma unroll
            for (int j = 0; j < 4; j++) w[j] = Ws[kk][tx + 16*j];
            #pragma unroll
            for (int i = 0; i < 2; i++)
                #pragma unroll
                for (int j = 0; j < 4; j++) {
                    E[i][j].x = fmaf(a[i].x, w[j].x, fmaf(-a[i].y, w[j].y, E[i][j].x));
                    E[i][j].y = fmaf(a[i].x, w[j].y, fmaf( a[i].y, w[j].x, E[i][j].y));
                    O[i][j].x = fmaf(a[i].z, w[j].x, fmaf(-a[i].w, w[j].y, O[i][j].x));
                    O[i][j].y = fmaf(a[i].z, w[j].y, fmaf( a[i].w, w[j].x, O[i][j].y));
                }
        }
        __syncthreads();
    }

    #pragma unroll
    for (int i = 0; i < 2; i++) {
        int r = r0 + ty*2 + i;
        if (r >= Mrows) continue;
        int img = r / HH;
        int col = r - img*HH;
        float2* outp = Aout + (size_t)img*NPIX;
        #pragma unroll
        for (int j = 0; j < 4; j++) {
            int v1 = v0 + tx + 16*j;
            if (v1 >= KH) continue;
            float2 t = tw542[v1];
            if (conjtw) t.y = -t.y;
            float2 Ev = E[i][j], Ov = O[i][j];
            float2 tO = make_float2(t.x*Ov.x - t.y*Ov.y, t.x*Ov.y + t.y*Ov.x);
            float2 lo = make_float2((Ev.x + tO.x)*scale, (Ev.y + tO.y)*scale);
            float2 hi = make_float2((Ev.x - tO.x)*scale, (Ev.y - tO.y)*scale);
            outp[(size_t)v1*HH + col]      = lo;
            outp[(size_t)(v1+KH)*HH + col] = hi;
        }
    }
}

extern "C" void kernel_launch(void* const* d_in, const int* in_sizes, int n_in,
                              void* d_out, int out_size, void* d_ws, size_t ws_size,
                              hipStream_t stream) {
    const float* y    = (const float*)d_in[0];
    const float* k    = (const float*)d_in[1];
    const float* lam  = (const float*)d_in[2];
    const float* filt = (const float*)d_in[3];
    float* out = (float*)d_out;

    char* base = (char*)d_ws;
    size_t off = 0;
    auto alloc = [&](size_t bytes) {
        void* p = base + off;
        off = (off + bytes + 511) & ~(size_t)511;
        return p;
    };
    float2* CA   = (float2*)alloc(sizeof(float2)*(size_t)NP*NPIX);
    float2* CB   = (float2*)alloc(sizeof(float2)*(size_t)NP*NPIX);
    float*  R0   = (float*) alloc(sizeof(float)*(size_t)NCH*NPIX);
    float2* Dk   = (float2*)alloc(sizeof(float2)*(size_t)BB*NPIX);
    float2* T1   = (float2*)alloc(sizeof(float2)*(size_t)BB*KSZ*HH);
    float*  Dgs  = (float*) alloc(sizeof(float)*(size_t)CC3*NPIX);
    float2* Wf   = (float2*)alloc(sizeof(float2)*(size_t)KH*KH);
    float2* Wi   = (float2*)alloc(sizeof(float2)*(size_t)KH*KH);
    float2* tw   = (float2*)alloc(sizeof(float2)*(size_t)HH);
    float*  valp = (float*) alloc(sizeof(float)*(size_t)BB*2*HH);
    (void)ws_size; (void)in_sizes; (void)n_in; (void)out_size;

    const int TPB = 256;
    auto nb = [](long n) { return (int)((n + 255)/256); };

    gen_tables<<<nb((long)KH*KH), TPB, 0, stream>>>(tw, Wf, Wi);
    alpha_kernel<<<BB, 64, 0, stream>>>(k, valp);
    dk_stage1<<<nb((long)BB*KSZ*HH), TPB, 0, stream>>>(k, tw, T1);
    dk_stage2<<<nb((long)BB*NPIX), TPB, 0, stream>>>(T1, tw, Dk);
    dgs_kernel<<<nb((long)NPIX), TPB, 0, stream>>>(filt, lam, tw, Dgs);
    pad_pack<<<nb((long)NP*NPIX), TPB, 0, stream>>>(y, R0, CA);

    dim3 pg((KH+63)/64, (MROWS+RT-1)/RT);
    const float isc = 1.0f/(float)HH;
    // forward fft2 of packed image: CA -> CB -> CA
    fft_pass<<<pg, TPB, 0, stream>>>(CA, CB, Wf, tw, 1.0f, 0, MROWS);
    fft_pass<<<pg, TPB, 0, stream>>>(CB, CA, Wf, tw, 1.0f, 0, MROWS);
    for (int it = 0; it < 3; it++) {
        specmul<<<nb((long)NP*NPIX), TPB, 0, stream>>>(CA, Dk, Dgs, CB, 0);
        fft_pass<<<pg, TPB, 0, stream>>>(CB, CA, Wi, tw, isc, 1, MROWS);
        fft_pass<<<pg, TPB, 0, stream>>>(CA, CB, Wi, tw, isc, 1, MROWS);
        blend_kernel<<<nb((long)NP*NPIX), TPB, 0, stream>>>(CB, valp, R0, CA);
        fft_pass<<<pg, TPB, 0, stream>>>(CA, CB, Wf, tw, 1.0f, 0, MROWS);
        fft_pass<<<pg, TPB, 0, stream>>>(CB, CA, Wf, tw, 1.0f, 0, MROWS);
    }
    specmul<<<nb((long)NP*NPIX), TPB, 0, stream>>>(CA, Dk, Dgs, CB, 1);
    fft_pass<<<pg, TPB, 0, stream>>>(CB, CA, Wi, tw, isc, 1, MROWS);
    fft_pass<<<pg, TPB, 0, stream>>>(CA, CB, Wi, tw, isc, 1, MROWS);
    out_kernel<<<nb((long)NP*NPIX), TPB, 0, stream>>>(CB, out);
}

// Round 3
// 1997.818 us; speedup vs baseline: 2.0981x; 1.1022x over previous
//
#include <hip/hip_runtime.h>
#include <cmath>

#define HH 542
#define KH 271
#define NPIX (HH*HH)          // 293764
#define BB 8
#define CC3 3
#define NCH (BB*CC3)          // 24 real channels
#define NP 12                 // 12 packed complex planes
#define MROWS (NP*HH)         // 6504 complex rows per pass
#define MR2 (2*MROWS)         // 13008 real GEMM rows (even/odd interleave)
#define KSZ 31
#define KRAD 15
#define NF 8
#define FS 3

#define NB 576                // padded phys N (288 re + 288 im)
#define KB 544                // padded K' (2*271 -> 544)
#define NSPLIT 3
#define BTSZ (NSPLIT*NB*KB)   // shorts per B-table

typedef __attribute__((ext_vector_type(8))) short short8v;
typedef __attribute__((ext_vector_type(4))) float float4v;

static __device__ __forceinline__ float2 cmul(float2 a, float2 b) {
    return make_float2(a.x*b.x - a.y*b.y, a.x*b.y + a.y*b.x);
}

// pair p -> the two real channel indices it packs (.x real side, .y imag side)
static __device__ __forceinline__ void pair_chans(int p, int& n1, int& n2) {
    if (p < 8) { n1 = 3*p;     n2 = 3*p + 1; }
    else       { int q = p-8; n1 = 6*q + 2; n2 = 6*q + 5; }
}

// truncation 3-way bf16 split of two adjacent values (x=low short, y=high short)
static __device__ __forceinline__ void split_pack_pair(float x, float y,
        unsigned& p0, unsigned& p1, unsigned& p2) {
    unsigned ux = __float_as_uint(x), uy = __float_as_uint(y);
    unsigned hx0 = ux & 0xffff0000u, hy0 = uy & 0xffff0000u;
    float rx1 = x - __uint_as_float(hx0);
    float ry1 = y - __uint_as_float(hy0);
    unsigned hx1 = __float_as_uint(rx1) & 0xffff0000u;
    unsigned hy1 = __float_as_uint(ry1) & 0xffff0000u;
    float rx2 = rx1 - __uint_as_float(hx1);
    float ry2 = ry1 - __uint_as_float(hy1);
    p0 = (hx0 >> 16) | hy0;
    p1 = (hx1 >> 16) | hy1;
    p2 = (__float_as_uint(rx2) >> 16) | (__float_as_uint(ry2) & 0xffff0000u);
}

// ---------------- tables: tw542 + split-bf16 B' matrices (fwd + inv), layout Bt[s][n][k']
__global__ void gen_tables(float2* tw542, short* Btf, short* Bti) {
    int idx = blockIdx.x*blockDim.x + threadIdx.x;
    const float PI2 = 6.283185307179586f;
    if (idx < HH) {
        float ang = -PI2*(float)idx/(float)HH;
        float s, c; sincosf(ang, &s, &c);
        tw542[idx] = make_float2(c, s);
    }
    if (idx >= NB*KB) return;
    int gcol = idx / KB, kp = idx - gcol*KB;
    int o  = (gcol >= 288) ? 1 : 0;
    int v1 = gcol - 288*o;
    int kidx = kp >> 1, c = kp & 1;
    float wre = 0.f, wim = 0.f;
    if (v1 < KH && kidx < KH) {
        int r = (kidx*v1) % KH;
        float ang = -PI2*(float)r/(float)KH;
        float s, cs; sincosf(ang, &s, &cs);
        wre = cs; wim = s;
    }
    // forward: w; inverse: conj(w)
    float vf = (o==0) ? ((c==0) ? wre : -wim) : ((c==0) ?  wim : wre);
    float vi = (o==0) ? ((c==0) ? wre :  wim) : ((c==0) ? -wim : wre);
    {
        unsigned u = __float_as_uint(vf);
        unsigned h0 = u & 0xffff0000u;
        float r1 = vf - __uint_as_float(h0);
        unsigned h1 = __float_as_uint(r1) & 0xffff0000u;
        float r2 = r1 - __uint_as_float(h1);
        Btf[0*NB*KB + idx] = (short)(h0 >> 16);
        Btf[1*NB*KB + idx] = (short)(h1 >> 16);
        Btf[2*NB*KB + idx] = (short)(__float_as_uint(r2) >> 16);
    }
    {
        unsigned u = __float_as_uint(vi);
        unsigned h0 = u & 0xffff0000u;
        float r1 = vi - __uint_as_float(h0);
        unsigned h1 = __float_as_uint(r1) & 0xffff0000u;
        float r2 = r1 - __uint_as_float(h1);
        Bti[0*NB*KB + idx] = (short)(h0 >> 16);
        Bti[1*NB*KB + idx] = (short)(h1 >> 16);
        Bti[2*NB*KB + idx] = (short)(__float_as_uint(r2) >> 16);
    }
}

// ---------------- edgetaper alpha vectors (closed-form autocorrelation)
__global__ void alpha_kernel(const float* __restrict__ kk, float* __restrict__ valpha) {
    int b = blockIdx.x;
    int t = threadIdx.x;
    __shared__ float proj[2][KSZ];
    __shared__ float ac[2][KSZ];
    const float* kb = kk + b*KSZ*KSZ;
    if (t < KSZ) {
        float s = 0;
        for (int j = 0; j < KSZ; j++) s += kb[t*KSZ + j];
        proj[0][t] = s;
    } else if (t >= 32 && t < 32+KSZ) {
        int j = t - 32;
        float s = 0;
        for (int i = 0; i < KSZ; i++) s += kb[i*KSZ + j];
        proj[1][j] = s;
    }
    __syncthreads();
    if (t < KSZ) {
        float s0 = 0, s1 = 0;
        for (int m = 0; m + t < KSZ; m++) {
            s0 += proj[0][m]*proj[0][m+t];
            s1 += proj[1][m]*proj[1][m+t];
        }
        ac[0][t] = s0; ac[1][t] = s1;
    }
    __syncthreads();
    float inv0 = 1.0f/ac[0][0];
    float inv1 = 1.0f/ac[1][0];
    for (int d = t; d < HH; d += blockDim.x) {
        for (int a = 0; a < 2; a++) {
            float z;
            if (d <= 30)                   z = ac[a][d];
            else if (d >= 511 && d <= 540) z = ac[a][541-d];
            else if (d == 541)             z = ac[a][0];
            else                           z = 0.0f;
            valpha[(b*2 + a)*HH + d] = 1.0f - z*(a ? inv1 : inv0);
        }
    }
}

// ---------------- Dk = psf2otf(k) via two small DFT stages
__global__ void dk_stage1(const float* __restrict__ kk, const float2* __restrict__ tw,
                          float2* __restrict__ T1) {
    int idx = blockIdx.x*blockDim.x + threadIdx.x;
    if (idx >= BB*KSZ*HH) return;
    int v  = idx % HH;
    int bm = idx / HH;
    int m  = bm % KSZ;
    int b  = bm / KSZ;
    const float* kb = kk + (b*KSZ + m)*KSZ;
    float2 acc = make_float2(0.f, 0.f);
    for (int n = 0; n < KSZ; n++) {
        int r = (v*(n - KRAD)) % HH;
        if (r < 0) r += HH;
        float2 w = tw[r];
        float kv = kb[n];
        acc.x = fmaf(kv, w.x, acc.x);
        acc.y = fmaf(kv, w.y, acc.y);
    }
    T1[idx] = acc;
}

__global__ void dk_stage2(const float2* __restrict__ T1, const float2* __restrict__ tw,
                          float2* __restrict__ Dk) {
    int idx = blockIdx.x*blockDim.x + threadIdx.x;
    if (idx >= BB*NPIX) return;
    int uv = idx % NPIX;
    int b  = idx / NPIX;
    int u  = uv / HH;
    int v  = uv - u*HH;
    float2 acc = make_float2(0.f, 0.f);
    for (int m = 0; m < KSZ; m++) {
        int r = (u*(m - KRAD)) % HH;
        if (r < 0) r += HH;
        float2 w = tw[r];
        float2 t = T1[(b*KSZ + m)*HH + v];
        acc.x += t.x*w.x - t.y*w.y;
        acc.y += t.x*w.y + t.y*w.x;
    }
    Dk[idx] = acc;
}

// ---------------- Dg_sum[c][u][v] = exp(lam)*sum_f |DFT(filt[f,c])|^2
__global__ void dgs_kernel(const float* __restrict__ filt, const float* __restrict__ lamp,
                           const float2* __restrict__ tw, float* __restrict__ Dgs) {
    int uv = blockIdx.x*blockDim.x + threadIdx.x;
    if (uv >= NPIX) return;
    int u = uv / HH;
    int v = uv - u*HH;
    float el = expf(lamp[0]);
    float2 ph[3][3];
    for (int m = 0; m < 3; m++) {
        int ru = (u*(m-1)) % HH; if (ru < 0) ru += HH;
        float2 wu = tw[ru];
        for (int n = 0; n < 3; n++) {
            int rv = (v*(n-1)) % HH; if (rv < 0) rv += HH;
            ph[m][n] = cmul(wu, tw[rv]);
        }
    }
    for (int c = 0; c < CC3; c++) {
        float s = 0.f;
        for (int f = 0; f < NF; f++) {
            float2 acc = make_float2(0.f, 0.f);
            const float* fp = filt + ((f*CC3 + c)*FS)*FS;
            #pragma unroll
            for (int m = 0; m < 3; m++)
                #pragma unroll
                for (int n = 0; n < 3; n++) {
                    float fv = fp[m*3+n];
                    acc.x = fmaf(fv, ph[m][n].x, acc.x);
                    acc.y = fmaf(fv, ph[m][n].y, acc.y);
                }
            s = fmaf(acc.x, acc.x, fmaf(acc.y, acc.y, s));
        }
        Dgs[c*NPIX + uv] = s*el;
    }
}

// ---------------- edge-replicate pad + pack pairs
__global__ void pad_pack(const float* __restrict__ y, float* __restrict__ R0,
                         float2* __restrict__ CA) {
    int idx = blockIdx.x*blockDim.x + threadIdx.x;
    if (idx >= NP*NPIX) return;
    int uv = idx % NPIX;
    int p  = idx / NPIX;
    int n1, n2; pair_chans(p, n1, n2);
    int i = uv / HH, j = uv - i*HH;
    int yi = min(max(i - KRAD, 0), 511);
    int yj = min(max(j - KRAD, 0), 511);
    int yo = yi*512 + yj;
    float v1 = y[(size_t)n1*262144 + yo];
    float v2 = y[(size_t)n2*262144 + yo];
    R0[(size_t)n1*NPIX + uv] = v1;
    R0[(size_t)n2*NPIX + uv] = v2;
    CA[idx] = make_float2(v1, v2);
}

// ---------------- Hermitian unpack, per-channel multiply, repack.
__global__ void specmul(const float2* __restrict__ CA, const float2* __restrict__ Dk,
                        const float* __restrict__ Dgs, float2* __restrict__ CB, int mode) {
    int idx = blockIdx.x*blockDim.x + threadIdx.x;
    if (idx >= NP*NPIX) return;
    int uv = idx % NPIX;
    int p  = idx / NPIX;
    int n1, n2; pair_chans(p, n1, n2);
    int b1 = n1/3, c1 = n1 - 3*b1;
    int b2 = n2/3, c2 = n2 - 3*b2;
    int i = uv / HH, j = uv - i*HH;
    int ni = i ? HH - i : 0;
    int nj = j ? HH - j : 0;
    float2 Z  = CA[(size_t)p*NPIX + uv];
    float2 Zm = CA[(size_t)p*NPIX + ni*HH + nj];
    float2 F1 = make_float2(0.5f*(Z.x + Zm.x), 0.5f*(Z.y - Zm.y));
    float2 F2 = make_float2(0.5f*(Z.y + Zm.y), 0.5f*(Zm.x - Z.x));
    float2 d1 = Dk[(size_t)b1*NPIX + uv];
    float2 d2 = Dk[(size_t)b2*NPIX + uv];
    float2 M1, M2;
    if (mode == 0) {
        M1 = d1; M2 = d2;
    } else {
        float o1 = 1.0f/(d1.x*d1.x + d1.y*d1.y + Dgs[(size_t)c1*NPIX + uv]);
        float o2 = 1.0f/(d2.x*d2.x + d2.y*d2.y + Dgs[(size_t)c2*NPIX + uv]);
        M1 = make_float2(d1.x*o1, -d1.y*o1);
        M2 = make_float2(d2.x*o2, -d2.y*o2);
    }
    float2 W1 = cmul(M1, F1);
    float2 W2 = cmul(M2, F2);
    CB[idx] = make_float2(W1.x - W2.y, W1.y + W2.x);
}

// ---------------- edgetaper blend
__global__ void blend_kernel(const float2* __restrict__ CB, const float* __restrict__ valpha,
                             float* __restrict__ R0, float2* __restrict__ CA) {
    int idx = blockIdx.x*blockDim.x + threadIdx.x;
    if (idx >= NP*NPIX) return;
    int uv = idx % NPIX;
    int p  = idx / NPIX;
    int n1, n2; pair_chans(p, n1, n2);
    int b1 = n1/3, b2 = n2/3;
    int i = uv / HH, j = uv - i*HH;
    float2 bl = CB[idx];
    float a1 = valpha[b1*2*HH + i] * valpha[(b1*2+1)*HH + j];
    float a2 = valpha[b2*2*HH + i] * valpha[(b2*2+1)*HH + j];
    float o1 = R0[(size_t)n1*NPIX + uv];
    float o2 = R0[(size_t)n2*NPIX + uv];
    float v1 = fmaf(a1, o1 - bl.x, bl.x);
    float v2 = fmaf(a2, o2 - bl.y, bl.y);
    R0[(size_t)n1*NPIX + uv] = v1;
    R0[(size_t)n2*NPIX + uv] = v2;
    CA[idx] = make_float2(v1, v2);
}

__global__ void out_kernel(const float2* __restrict__ CB, float* __restrict__ out) {
    int idx = blockIdx.x*blockDim.x + threadIdx.x;
    if (idx >= NP*NPIX) return;
    int uv = idx % NPIX;
    int p  = idx / NPIX;
    int n1, n2; pair_chans(p, n1, n2);
    float2 v = CB[idx];
    out[(size_t)n1*NPIX + uv] = v.x;
    out[(size_t)n2*NPIX + uv] = v.y;
}

// ---------------- MFMA DFT pass: real GEMM M=13008 x N=(271v1 x re/im) x K=544,
// bf16x3 split, 6 products, fp32 accumulate. WG tile: 128M x 32v1 (64 phys cols).
// Epilogue: split-radix twiddle combine, transposed write. 2 passes = fft2.
__global__ void __launch_bounds__(256)
fft_mfma(const float2* __restrict__ Ain, float2* __restrict__ Aout,
         const short* __restrict__ Bt, const float2* __restrict__ tw542,
         float scale, int conjtw)
{
    __shared__ short As[NSPLIT*128*40];   // [s][row 128][k' 32 pad40]
    __shared__ short Bs[NSPLIT*64*40];    // [s][n 64][k' 32 pad40]
    const int APL = 128*40, BPL = 64*40;

    int tid = threadIdx.x;
    int bx = blockIdx.x;   // v1-block (32 v1 each), 0..8
    int by = blockIdx.y;   // M-block (128 A'rows = 64 complex rows), 0..101

    // ---- staging roles
    int arow = tid >> 3;          // 0..31 (+32 for q=1): local complex row
    int ai4  = tid & 7;           // float4-pair index
    int bn   = tid >> 2;          // 0..63: local B col
    int bk8  = tid & 3;           // 8-k' group
    int gcol = (bn < 32) ? (bx*32 + bn) : (288 + bx*32 + (bn - 32));

    // ---- wave roles
    int wid = tid >> 6, lane = tid & 63;
    int wxm = wid & 1, wy = wid >> 1;
    int l15 = lane & 15, quad = lane >> 4;

    int aoff0 = (wxm*64 + l15)*40 + quad*8;      // + mt*640 + s*APL
    int boffR = (wy*16 + l15)*40 + quad*8;       // + s*BPL
    int boffI = boffR + 32*40;

    float4v acc[4][2];
    #pragma unroll
    for (int mt = 0; mt < 4; mt++)
        #pragma unroll
        for (int ct = 0; ct < 2; ct++)
            acc[mt][ct] = (float4v)(0.f);

    float4 regA[2][2];
    uint4  regB[3];
    const float4 z4 = make_float4(0.f,0.f,0.f,0.f);

    auto loadA = [&](int step) {
        #pragma unroll
        for (int qq = 0; qq < 2; qq++) {
            int rowg = by*64 + arow + 32*qq;
            bool rvld = rowg < MROWS;
            const float4* rp = (const float4*)Ain + (size_t)(rvld ? rowg : 0)*271;
            int i0 = step*16 + 2*ai4;
            regA[qq][0] = (rvld && i0     < 271) ? rp[i0]   : z4;
            regA[qq][1] = (rvld && i0 + 1 < 271) ? rp[i0+1] : z4;
        }
    };
    auto loadB = [&](int step) {
        #pragma unroll
        for (int s = 0; s < 3; s++)
            regB[s] = *(const uint4*)(Bt + (size_t)s*(NB*KB) + (size_t)gcol*KB + step*32 + bk8*8);
    };

    loadA(0); loadB(0);

    for (int step = 0; step < 17; step++) {
        // regs -> LDS (split A on the fly)
        #pragma unroll
        for (int qq = 0; qq < 2; qq++) {
            int rl = 2*(arow + 32*qq);
            int offE = rl*40 + 4*ai4;
            float4 f0 = regA[qq][0], f1 = regA[qq][1];
            unsigned e0a,e1a,e2a, e0b,e1b,e2b;
            split_pack_pair(f0.x, f0.y, e0a, e1a, e2a);
            split_pack_pair(f1.x, f1.y, e0b, e1b, e2b);
            *(uint2*)(As + 0*APL + offE) = make_uint2(e0a, e0b);
            *(uint2*)(As + 1*APL + offE) = make_uint2(e1a, e1b);
            *(uint2*)(As + 2*APL + offE) = make_uint2(e2a, e2b);
            unsigned o0a,o1a,o2a, o0b,o1b,o2b;
            split_pack_pair(f0.z, f0.w, o0a, o1a, o2a);
            split_pack_pair(f1.z, f1.w, o0b, o1b, o2b);
            int offO = offE + 40;
            *(uint2*)(As + 0*APL + offO) = make_uint2(o0a, o0b);
            *(uint2*)(As + 1*APL + offO) = make_uint2(o1a, o1b);
            *(uint2*)(As + 2*APL + offO) = make_uint2(o2a, o2b);
        }
        #pragma unroll
        for (int s = 0; s < 3; s++)
            *(uint4*)(Bs + s*BPL + bn*40 + bk8*8) = regB[s];
        __syncthreads();

        if (step + 1 < 17) { loadA(step+1); loadB(step+1); }

        short8v af[4][3], bf[2][3];
        #pragma unroll
        for (int s = 0; s < 3; s++) {
            #pragma unroll
            for (int mt = 0; mt < 4; mt++)
                af[mt][s] = *(const short8v*)(As + s*APL + aoff0 + mt*16*40);
            bf[0][s] = *(const short8v*)(Bs + s*BPL + boffR);
            bf[1][s] = *(const short8v*)(Bs + s*BPL + boffI);
        }
        const int SA[6] = {0,0,1,0,1,2};
        const int SB[6] = {0,1,0,2,1,0};
        #pragma unroll
        for (int pr = 0; pr < 6; pr++)
            #pragma unroll
            for (int mt = 0; mt < 4; mt++)
                #pragma unroll
                for (int ct = 0; ct < 2; ct++)
                    acc[mt][ct] = __builtin_amdgcn_mfma_f32_16x16x32_bf16(
                        af[mt][SA[pr]], bf[ct][SB[pr]], acc[mt][ct], 0, 0, 0);
        __syncthreads();
    }

    // ---- epilogue: twiddle combine + transposed scatter
    int v1 = bx*32 + wy*16 + l15;
    if (v1 >= KH) return;
    float2 t = tw542[v1];
    if (conjtw) t.y = -t.y;
    #pragma unroll
    for (int mt = 0; mt < 4; mt++) {
        int rbase = by*128 + wxm*64 + mt*16 + quad*4;
        #pragma unroll
        for (int pr = 0; pr < 2; pr++) {
            int rowE = rbase + 2*pr;
            if (rowE >= MR2) continue;
            int r = rowE >> 1;
            int plane = r / HH;
            int col = r - plane*HH;
            float Ere = acc[mt][0][2*pr + 0];
            float Ore = acc[mt][0][2*pr + 1];
            float Eim = acc[mt][1][2*pr + 0];
            float Oim = acc[mt][1][2*pr + 1];
            float tOre = t.x*Ore - t.y*Oim;
            float tOim = t.x*Oim + t.y*Ore;
            float2* outp = Aout + (size_t)plane*NPIX;
            outp[(size_t)v1*HH + col]      = make_float2((Ere + tOre)*scale, (Eim + tOim)*scale);
            outp[(size_t)(v1+KH)*HH + col] = make_float2((Ere - tOre)*scale, (Eim - tOim)*scale);
        }
    }
}

extern "C" void kernel_launch(void* const* d_in, const int* in_sizes, int n_in,
                              void* d_out, int out_size, void* d_ws, size_t ws_size,
                              hipStream_t stream) {
    const float* y    = (const float*)d_in[0];
    const float* k    = (const float*)d_in[1];
    const float* lam  = (const float*)d_in[2];
    const float* filt = (const float*)d_in[3];
    float* out = (float*)d_out;

    char* base = (char*)d_ws;
    size_t off = 0;
    auto alloc = [&](size_t bytes) {
        void* p = base + off;
        off = (off + bytes + 511) & ~(size_t)511;
        return p;
    };
    float2* CA   = (float2*)alloc(sizeof(float2)*(size_t)NP*NPIX);
    float2* CB   = (float2*)alloc(sizeof(float2)*(size_t)NP*NPIX);
    float*  R0   = (float*) alloc(sizeof(float)*(size_t)NCH*NPIX);
    float2* Dk   = (float2*)alloc(sizeof(float2)*(size_t)BB*NPIX);
    float2* T1   = (float2*)alloc(sizeof(float2)*(size_t)BB*KSZ*HH);
    float*  Dgs  = (float*) alloc(sizeof(float)*(size_t)CC3*NPIX);
    short*  Btf  = (short*) alloc(sizeof(short)*(size_t)BTSZ);
    short*  Bti  = (short*) alloc(sizeof(short)*(size_t)BTSZ);
    float2* tw   = (float2*)alloc(sizeof(float2)*(size_t)HH);
    float*  valp = (float*) alloc(sizeof(float)*(size_t)BB*2*HH);
    (void)ws_size; (void)in_sizes; (void)n_in; (void)out_size;

    const int TPB = 256;
    auto nb = [](long n) { return (int)((n + 255)/256); };

    gen_tables<<<nb((long)NB*KB), TPB, 0, stream>>>(tw, Btf, Bti);
    alpha_kernel<<<BB, 64, 0, stream>>>(k, valp);
    dk_stage1<<<nb((long)BB*KSZ*HH), TPB, 0, stream>>>(k, tw, T1);
    dk_stage2<<<nb((long)BB*NPIX), TPB, 0, stream>>>(T1, tw, Dk);
    dgs_kernel<<<nb((long)NPIX), TPB, 0, stream>>>(filt, lam, tw, Dgs);
    pad_pack<<<nb((long)NP*NPIX), TPB, 0, stream>>>(y, R0, CA);

    dim3 pg(9, (MR2 + 127)/128);   // 9 x 102
    const float isc = 1.0f/(float)HH;
    fft_mfma<<<pg, TPB, 0, stream>>>(CA, CB, Btf, tw, 1.0f, 0);
    fft_mfma<<<pg, TPB, 0, stream>>>(CB, CA, Btf, tw, 1.0f, 0);
    for (int it = 0; it < 3; it++) {
        specmul<<<nb((long)NP*NPIX), TPB, 0, stream>>>(CA, Dk, Dgs, CB, 0);
        fft_mfma<<<pg, TPB, 0, stream>>>(CB, CA, Bti, tw, isc, 1);
        fft_mfma<<<pg, TPB, 0, stream>>>(CA, CB, Bti, tw, isc, 1);
        blend_kernel<<<nb((long)NP*NPIX), TPB, 0, stream>>>(CB, valp, R0, CA);
        fft_mfma<<<pg, TPB, 0, stream>>>(CA, CB, Btf, tw, 1.0f, 0);
        fft_mfma<<<pg, TPB, 0, stream>>>(CB, CA, Btf, tw, 1.0f, 0);
    }
    specmul<<<nb((long)NP*NPIX), TPB, 0, stream>>>(CA, Dk, Dgs, CB, 1);
    fft_mfma<<<pg, TPB, 0, stream>>>(CB, CA, Bti, tw, isc, 1);
    fft_mfma<<<pg, TPB, 0, stream>>>(CA, CB, Bti, tw, isc, 1);
    out_kernel<<<nb((long)NP*NPIX), TPB, 0, stream>>>(CB, out);
}

// Round 4
// 1306.026 us; speedup vs baseline: 3.2095x; 1.5297x over previous
//
#include <hip/hip_runtime.h>
#include <cmath>

#define HH 542
#define KH 271
#define NPIX (HH*HH)          // 293764
#define BB 8
#define CC3 3
#define NCH (BB*CC3)          // 24 real channels
#define NP 12                 // 12 packed complex planes
#define MROWS (NP*HH)         // 6504 complex rows per pass
#define MR2 (2*MROWS)         // 13008 real GEMM rows
#define KSZ 31
#define KRAD 15
#define NF 8
#define FS 3

#define NSPLIT 3
#define NGRP 36               // 576 phys cols / 16
#define BTSZ (NGRP*NSPLIT*17*512)  // shorts per fragment-ordered B-table (940032)

typedef __attribute__((ext_vector_type(8))) short short8v;
typedef __attribute__((ext_vector_type(4))) float float4v;

static __device__ __forceinline__ float2 cmul(float2 a, float2 b) {
    return make_float2(a.x*b.x - a.y*b.y, a.x*b.y + a.y*b.x);
}

static __device__ __forceinline__ void pair_chans(int p, int& n1, int& n2) {
    if (p < 8) { n1 = 3*p;     n2 = 3*p + 1; }
    else       { int q = p-8; n1 = 6*q + 2; n2 = 6*q + 5; }
}

// truncation 3-way bf16 split of two adjacent values (x=low short, y=high short)
static __device__ __forceinline__ void split_pack_pair(float x, float y,
        unsigned& p0, unsigned& p1, unsigned& p2) {
    unsigned ux = __float_as_uint(x), uy = __float_as_uint(y);
    unsigned hx0 = ux & 0xffff0000u, hy0 = uy & 0xffff0000u;
    float rx1 = x - __uint_as_float(hx0);
    float ry1 = y - __uint_as_float(hy0);
    unsigned hx1 = __float_as_uint(rx1) & 0xffff0000u;
    unsigned hy1 = __float_as_uint(ry1) & 0xffff0000u;
    float rx2 = rx1 - __uint_as_float(hx1);
    float ry2 = ry1 - __uint_as_float(hy1);
    p0 = (hx0 >> 16) | hy0;
    p1 = (hx1 >> 16) | hy1;
    p2 = (__float_as_uint(rx2) >> 16) | (__float_as_uint(ry2) & 0xffff0000u);
}

// ---------------- tables: tw542 + fragment-ordered split-bf16 B tables.
// Bt[((g*3+s)*17+step)*512 + lane*8 + j] = split_s of B'[n = g*16 + (lane&15)]
//                                               [k' = step*32 + (lane>>4)*8 + j]
__global__ void gen_tables(float2* tw542, short* Btf, short* Bti) {
    int idx = blockIdx.x*blockDim.x + threadIdx.x;
    const float PI2 = 6.283185307179586f;
    if (idx < HH) {
        float ang = -PI2*(float)idx/(float)HH;
        float s, c; sincosf(ang, &s, &c);
        tw542[idx] = make_float2(c, s);
    }
    if (idx >= BTSZ) return;
    int j    = idx & 7;
    int lane = (idx >> 3) & 63;
    int rem  = idx >> 9;
    int step = rem % 17;
    int rem2 = rem / 17;
    int s    = rem2 % 3;
    int g    = rem2 / 3;
    if (g >= NGRP) return;
    int n  = g*16 + (lane & 15);
    int kq = step*32 + (lane >> 4)*8 + j;
    int o  = (n >= 288) ? 1 : 0;
    int v1 = n - 288*o;
    int kidx = kq >> 1, c = kq & 1;
    float wre = 0.f, wim = 0.f;
    if (v1 < KH && kidx < KH) {
        int r = (kidx*v1) % KH;
        float ang = -PI2*(float)r/(float)KH;
        float sn, cs; sincosf(ang, &sn, &cs);
        wre = cs; wim = sn;
    }
    float vf = (o==0) ? ((c==0) ? wre : -wim) : ((c==0) ?  wim : wre);
    float vi = (o==0) ? ((c==0) ? wre :  wim) : ((c==0) ? -wim : wre);
    {
        unsigned u = __float_as_uint(vf);
        unsigned h0 = u & 0xffff0000u;
        float r1 = vf - __uint_as_float(h0);
        unsigned h1 = __float_as_uint(r1) & 0xffff0000u;
        float r2 = r1 - __uint_as_float(h1);
        unsigned sp = (s==0) ? h0 : (s==1) ? h1 : (__float_as_uint(r2) & 0xffff0000u);
        Btf[idx] = (short)(sp >> 16);
    }
    {
        unsigned u = __float_as_uint(vi);
        unsigned h0 = u & 0xffff0000u;
        float r1 = vi - __uint_as_float(h0);
        unsigned h1 = __float_as_uint(r1) & 0xffff0000u;
        float r2 = r1 - __uint_as_float(h1);
        unsigned sp = (s==0) ? h0 : (s==1) ? h1 : (__float_as_uint(r2) & 0xffff0000u);
        Bti[idx] = (short)(sp >> 16);
    }
}

// ---------------- edgetaper alpha vectors (closed-form autocorrelation)
__global__ void alpha_kernel(const float* __restrict__ kk, float* __restrict__ valpha) {
    int b = blockIdx.x;
    int t = threadIdx.x;
    __shared__ float proj[2][KSZ];
    __shared__ float ac[2][KSZ];
    const float* kb = kk + b*KSZ*KSZ;
    if (t < KSZ) {
        float s = 0;
        for (int j = 0; j < KSZ; j++) s += kb[t*KSZ + j];
        proj[0][t] = s;
    } else if (t >= 32 && t < 32+KSZ) {
        int j = t - 32;
        float s = 0;
        for (int i = 0; i < KSZ; i++) s += kb[i*KSZ + j];
        proj[1][j] = s;
    }
    __syncthreads();
    if (t < KSZ) {
        float s0 = 0, s1 = 0;
        for (int m = 0; m + t < KSZ; m++) {
            s0 += proj[0][m]*proj[0][m+t];
            s1 += proj[1][m]*proj[1][m+t];
        }
        ac[0][t] = s0; ac[1][t] = s1;
    }
    __syncthreads();
    float inv0 = 1.0f/ac[0][0];
    float inv1 = 1.0f/ac[1][0];
    for (int d = t; d < HH; d += blockDim.x) {
        for (int a = 0; a < 2; a++) {
            float z;
            if (d <= 30)                   z = ac[a][d];
            else if (d >= 511 && d <= 540) z = ac[a][541-d];
            else if (d == 541)             z = ac[a][0];
            else                           z = 0.0f;
            valpha[(b*2 + a)*HH + d] = 1.0f - z*(a ? inv1 : inv0);
        }
    }
}

// ---------------- Dk = psf2otf(k) via two small DFT stages
__global__ void dk_stage1(const float* __restrict__ kk, const float2* __restrict__ tw,
                          float2* __restrict__ T1) {
    int idx = blockIdx.x*blockDim.x + threadIdx.x;
    if (idx >= BB*KSZ*HH) return;
    int v  = idx % HH;
    int bm = idx / HH;
    int m  = bm % KSZ;
    int b  = bm / KSZ;
    const float* kb = kk + (b*KSZ + m)*KSZ;
    float2 acc = make_float2(0.f, 0.f);
    for (int n = 0; n < KSZ; n++) {
        int r = (v*(n - KRAD)) % HH;
        if (r < 0) r += HH;
        float2 w = tw[r];
        float kv = kb[n];
        acc.x = fmaf(kv, w.x, acc.x);
        acc.y = fmaf(kv, w.y, acc.y);
    }
    T1[idx] = acc;
}

__global__ void dk_stage2(const float2* __restrict__ T1, const float2* __restrict__ tw,
                          float2* __restrict__ Dk) {
    int idx = blockIdx.x*blockDim.x + threadIdx.x;
    if (idx >= BB*NPIX) return;
    int uv = idx % NPIX;
    int b  = idx / NPIX;
    int u  = uv / HH;
    int v  = uv - u*HH;
    float2 acc = make_float2(0.f, 0.f);
    for (int m = 0; m < KSZ; m++) {
        int r = (u*(m - KRAD)) % HH;
        if (r < 0) r += HH;
        float2 w = tw[r];
        float2 t = T1[(b*KSZ + m)*HH + v];
        acc.x += t.x*w.x - t.y*w.y;
        acc.y += t.x*w.y + t.y*w.x;
    }
    Dk[idx] = acc;
}

// ---------------- Dg_sum[c][u][v] = exp(lam)*sum_f |DFT(filt[f,c])|^2
__global__ void dgs_kernel(const float* __restrict__ filt, const float* __restrict__ lamp,
                           const float2* __restrict__ tw, float* __restrict__ Dgs) {
    int uv = blockIdx.x*blockDim.x + threadIdx.x;
    if (uv >= NPIX) return;
    int u = uv / HH;
    int v = uv - u*HH;
    float el = expf(lamp[0]);
    float2 ph[3][3];
    for (int m = 0; m < 3; m++) {
        int ru = (u*(m-1)) % HH; if (ru < 0) ru += HH;
        float2 wu = tw[ru];
        for (int n = 0; n < 3; n++) {
            int rv = (v*(n-1)) % HH; if (rv < 0) rv += HH;
            ph[m][n] = cmul(wu, tw[rv]);
        }
    }
    for (int c = 0; c < CC3; c++) {
        float s = 0.f;
        for (int f = 0; f < NF; f++) {
            float2 acc = make_float2(0.f, 0.f);
            const float* fp = filt + ((f*CC3 + c)*FS)*FS;
            #pragma unroll
            for (int m = 0; m < 3; m++)
                #pragma unroll
                for (int n = 0; n < 3; n++) {
                    float fv = fp[m*3+n];
                    acc.x = fmaf(fv, ph[m][n].x, acc.x);
                    acc.y = fmaf(fv, ph[m][n].y, acc.y);
                }
            s = fmaf(acc.x, acc.x, fmaf(acc.y, acc.y, s));
        }
        Dgs[c*NPIX + uv] = s*el;
    }
}

// ---------------- edge-replicate pad + pack pairs
__global__ void pad_pack(const float* __restrict__ y, float* __restrict__ R0,
                         float2* __restrict__ CA) {
    int idx = blockIdx.x*blockDim.x + threadIdx.x;
    if (idx >= NP*NPIX) return;
    int uv = idx % NPIX;
    int p  = idx / NPIX;
    int n1, n2; pair_chans(p, n1, n2);
    int i = uv / HH, j = uv - i*HH;
    int yi = min(max(i - KRAD, 0), 511);
    int yj = min(max(j - KRAD, 0), 511);
    int yo = yi*512 + yj;
    float v1 = y[(size_t)n1*262144 + yo];
    float v2 = y[(size_t)n2*262144 + yo];
    R0[(size_t)n1*NPIX + uv] = v1;
    R0[(size_t)n2*NPIX + uv] = v2;
    CA[idx] = make_float2(v1, v2);
}

// ---------------- Hermitian unpack, per-channel multiply, repack.
__global__ void specmul(const float2* __restrict__ CA, const float2* __restrict__ Dk,
                        const float* __restrict__ Dgs, float2* __restrict__ CB, int mode) {
    int idx = blockIdx.x*blockDim.x + threadIdx.x;
    if (idx >= NP*NPIX) return;
    int uv = idx % NPIX;
    int p  = idx / NPIX;
    int n1, n2; pair_chans(p, n1, n2);
    int b1 = n1/3, c1 = n1 - 3*b1;
    int b2 = n2/3, c2 = n2 - 3*b2;
    int i = uv / HH, j = uv - i*HH;
    int ni = i ? HH - i : 0;
    int nj = j ? HH - j : 0;
    float2 Z  = CA[(size_t)p*NPIX + uv];
    float2 Zm = CA[(size_t)p*NPIX + ni*HH + nj];
    float2 F1 = make_float2(0.5f*(Z.x + Zm.x), 0.5f*(Z.y - Zm.y));
    float2 F2 = make_float2(0.5f*(Z.y + Zm.y), 0.5f*(Zm.x - Z.x));
    float2 d1 = Dk[(size_t)b1*NPIX + uv];
    float2 d2 = Dk[(size_t)b2*NPIX + uv];
    float2 M1, M2;
    if (mode == 0) {
        M1 = d1; M2 = d2;
    } else {
        float o1 = 1.0f/(d1.x*d1.x + d1.y*d1.y + Dgs[(size_t)c1*NPIX + uv]);
        float o2 = 1.0f/(d2.x*d2.x + d2.y*d2.y + Dgs[(size_t)c2*NPIX + uv]);
        M1 = make_float2(d1.x*o1, -d1.y*o1);
        M2 = make_float2(d2.x*o2, -d2.y*o2);
    }
    float2 W1 = cmul(M1, F1);
    float2 W2 = cmul(M2, F2);
    CB[idx] = make_float2(W1.x - W2.y, W1.y + W2.x);
}

// ---------------- edgetaper blend
__global__ void blend_kernel(const float2* __restrict__ CB, const float* __restrict__ valpha,
                             float* __restrict__ R0, float2* __restrict__ CA) {
    int idx = blockIdx.x*blockDim.x + threadIdx.x;
    if (idx >= NP*NPIX) return;
    int uv = idx % NPIX;
    int p  = idx / NPIX;
    int n1, n2; pair_chans(p, n1, n2);
    int b1 = n1/3, b2 = n2/3;
    int i = uv / HH, j = uv - i*HH;
    float2 bl = CB[idx];
    float a1 = valpha[b1*2*HH + i] * valpha[(b1*2+1)*HH + j];
    float a2 = valpha[b2*2*HH + i] * valpha[(b2*2+1)*HH + j];
    float o1 = R0[(size_t)n1*NPIX + uv];
    float o2 = R0[(size_t)n2*NPIX + uv];
    float v1 = fmaf(a1, o1 - bl.x, bl.x);
    float v2 = fmaf(a2, o2 - bl.y, bl.y);
    R0[(size_t)n1*NPIX + uv] = v1;
    R0[(size_t)n2*NPIX + uv] = v2;
    CA[idx] = make_float2(v1, v2);
}

__global__ void out_kernel(const float2* __restrict__ CB, float* __restrict__ out) {
    int idx = blockIdx.x*blockDim.x + threadIdx.x;
    if (idx >= NP*NPIX) return;
    int uv = idx % NPIX;
    int p  = idx / NPIX;
    int n1, n2; pair_chans(p, n1, n2);
    float2 v = CB[idx];
    out[(size_t)n1*NPIX + uv] = v.x;
    out[(size_t)n2*NPIX + uv] = v.y;
}

// ---------------- MFMA DFT pass. A staged+split in LDS; B fragments loaded
// directly from L2-resident fragment-ordered table; epilogue transposes the
// 32v1 x 64col tile through LDS for coalesced writes. XCD-swizzled grid.
__global__ void __launch_bounds__(256, 3)
fft_mfma(const float2* __restrict__ Ain, float2* __restrict__ Aout,
         const short* __restrict__ Bt, const float2* __restrict__ tw542,
         float scale, int conjtw)
{
    __shared__ short As[NSPLIT*128*40];   // 30720 B; reused as float2 Ts[32][65] in epilogue
    const int APL = 128*40;

    // XCD-locality swizzle: all 9 bx of a by-group on one XCD, adjacent in time
    int id = blockIdx.x;
    int xcd = id & 7, jj = id >> 3;
    int lin = xcd*115 + jj;
    if (lin >= 918) return;
    int by = lin / 9, bx = lin - 9*by;

    int tid = threadIdx.x;
    int arow = tid >> 3, ai4 = tid & 7;     // A staging roles
    int wid = tid >> 6, lane = tid & 63;
    int wxm = wid & 1, wy = wid >> 1;
    int l15 = lane & 15, quad = lane >> 4;

    int aoff0 = (wxm*64 + l15)*40 + quad*8;

    int g_re = bx*2 + wy;                   // 16-col group indices in B-table
    int g_im = 18 + bx*2 + wy;
    const short* BtL = Bt + lane*8;

    float4v acc[4][2];
    #pragma unroll
    for (int mt = 0; mt < 4; mt++)
        #pragma unroll
        for (int ct = 0; ct < 2; ct++)
            acc[mt][ct] = (float4v)(0.f);

    float4 regA[2][2];
    short8v bf_cur[2][3], bf_next[2][3];
    const float4 z4 = make_float4(0.f,0.f,0.f,0.f);

    auto loadA = [&](int step) {
        #pragma unroll
        for (int qq = 0; qq < 2; qq++) {
            int rowg = by*64 + arow + 32*qq;
            bool rvld = rowg < MROWS;
            const float4* rp = (const float4*)Ain + (size_t)(rvld ? rowg : 0)*271;
            int i0 = step*16 + 2*ai4;
            regA[qq][0] = (rvld && i0     < 271) ? rp[i0]   : z4;
            regA[qq][1] = (rvld && i0 + 1 < 271) ? rp[i0+1] : z4;
        }
    };
    auto loadB = [&](int step, short8v dst[2][3]) {
        #pragma unroll
        for (int s = 0; s < 3; s++) {
            dst[0][s] = *(const short8v*)(BtL + (((g_re*3 + s)*17 + step) << 9));
            dst[1][s] = *(const short8v*)(BtL + (((g_im*3 + s)*17 + step) << 9));
        }
    };

    loadA(0); loadB(0, bf_cur);

    for (int step = 0; step < 17; step++) {
        // stage A into LDS with 3-way bf16 split
        #pragma unroll
        for (int qq = 0; qq < 2; qq++) {
            int rl = 2*(arow + 32*qq);
            int offE = rl*40 + 4*ai4;
            float4 f0 = regA[qq][0], f1 = regA[qq][1];
            unsigned e0a,e1a,e2a, e0b,e1b,e2b;
            split_pack_pair(f0.x, f0.y, e0a, e1a, e2a);
            split_pack_pair(f1.x, f1.y, e0b, e1b, e2b);
            *(uint2*)(As + 0*APL + offE) = make_uint2(e0a, e0b);
            *(uint2*)(As + 1*APL + offE) = make_uint2(e1a, e1b);
            *(uint2*)(As + 2*APL + offE) = make_uint2(e2a, e2b);
            unsigned o0a,o1a,o2a, o0b,o1b,o2b;
            split_pack_pair(f0.z, f0.w, o0a, o1a, o2a);
            split_pack_pair(f1.z, f1.w, o0b, o1b, o2b);
            int offO = offE + 40;
            *(uint2*)(As + 0*APL + offO) = make_uint2(o0a, o0b);
            *(uint2*)(As + 1*APL + offO) = make_uint2(o1a, o1b);
            *(uint2*)(As + 2*APL + offO) = make_uint2(o2a, o2b);
        }
        __syncthreads();

        if (step + 1 < 17) { loadA(step+1); loadB(step+1, bf_next); }

        #pragma unroll
        for (int sa = 0; sa < 3; sa++) {
            short8v af[4];
            #pragma unroll
            for (int mt = 0; mt < 4; mt++)
                af[mt] = *(const short8v*)(As + sa*APL + aoff0 + mt*16*40);
            #pragma unroll
            for (int sb = 0; sb + sa < 3; sb++)
                #pragma unroll
                for (int mt = 0; mt < 4; mt++)
                    #pragma unroll
                    for (int ct = 0; ct < 2; ct++)
                        acc[mt][ct] = __builtin_amdgcn_mfma_f32_16x16x32_bf16(
                            af[mt], bf_cur[ct][sb], acc[mt][ct], 0, 0, 0);
        }
        __syncthreads();

        #pragma unroll
        for (int ct = 0; ct < 2; ct++)
            #pragma unroll
            for (int s = 0; s < 3; s++)
                bf_cur[ct][s] = bf_next[ct][s];
    }

    // ---- epilogue: twiddle combine, LDS transpose, coalesced writes
    int v1w = bx*32 + wy*16 + l15;
    float2 t = (v1w < KH) ? tw542[v1w] : make_float2(1.f, 0.f);
    if (conjtw) t.y = -t.y;
    float2* Ts = (float2*)As;    // [32][65] pitch-65 float2 = 16640 B

    #pragma unroll
    for (int half = 0; half < 2; half++) {
        __syncthreads();
        #pragma unroll
        for (int mt = 0; mt < 4; mt++) {
            #pragma unroll
            for (int pr = 0; pr < 2; pr++) {
                float Ere = acc[mt][0][2*pr],   Ore = acc[mt][0][2*pr+1];
                float Eim = acc[mt][1][2*pr],   Oim = acc[mt][1][2*pr+1];
                float tOre = t.x*Ore - t.y*Oim;
                float tOim = t.x*Oim + t.y*Ore;
                int cloc = wxm*32 + mt*8 + quad*2 + pr;
                float2 v = (half == 0)
                    ? make_float2((Ere + tOre)*scale, (Eim + tOim)*scale)
                    : make_float2((Ere - tOre)*scale, (Eim - tOim)*scale);
                Ts[(wy*16 + l15)*65 + cloc] = v;
            }
        }
        __syncthreads();
        int tv = tid >> 3, ti = tid & 7;
        bool v1ok = (bx*32 + tv) < KH;
        int v1 = bx*32 + tv + (half ? KH : 0);
        #pragma unroll
        for (int j = 0; j < 8; j++) {
            int cloc = ti*8 + j;
            int r = by*64 + cloc;
            if (v1ok && r < MROWS) {
                int plane = r / HH;
                int col = r - plane*HH;
                Aout[(size_t)plane*NPIX + (size_t)v1*HH + col] = Ts[tv*65 + cloc];
            }
        }
    }
}

extern "C" void kernel_launch(void* const* d_in, const int* in_sizes, int n_in,
                              void* d_out, int out_size, void* d_ws, size_t ws_size,
                              hipStream_t stream) {
    const float* y    = (const float*)d_in[0];
    const float* k    = (const float*)d_in[1];
    const float* lam  = (const float*)d_in[2];
    const float* filt = (const float*)d_in[3];
    float* out = (float*)d_out;

    char* base = (char*)d_ws;
    size_t off = 0;
    auto alloc = [&](size_t bytes) {
        void* p = base + off;
        off = (off + bytes + 511) & ~(size_t)511;
        return p;
    };
    float2* CA   = (float2*)alloc(sizeof(float2)*(size_t)NP*NPIX);
    float2* CB   = (float2*)alloc(sizeof(float2)*(size_t)NP*NPIX);
    float*  R0   = (float*) alloc(sizeof(float)*(size_t)NCH*NPIX);
    float2* Dk   = (float2*)alloc(sizeof(float2)*(size_t)BB*NPIX);
    float2* T1   = (float2*)alloc(sizeof(float2)*(size_t)BB*KSZ*HH);
    float*  Dgs  = (float*) alloc(sizeof(float)*(size_t)CC3*NPIX);
    short*  Btf  = (short*) alloc(sizeof(short)*(size_t)BTSZ);
    short*  Bti  = (short*) alloc(sizeof(short)*(size_t)BTSZ);
    float2* tw   = (float2*)alloc(sizeof(float2)*(size_t)HH);
    float*  valp = (float*) alloc(sizeof(float)*(size_t)BB*2*HH);
    (void)ws_size; (void)in_sizes; (void)n_in; (void)out_size;

    const int TPB = 256;
    auto nb = [](long n) { return (int)((n + 255)/256); };

    gen_tables<<<nb((long)BTSZ), TPB, 0, stream>>>(tw, Btf, Bti);
    alpha_kernel<<<BB, 64, 0, stream>>>(k, valp);
    dk_stage1<<<nb((long)BB*KSZ*HH), TPB, 0, stream>>>(k, tw, T1);
    dk_stage2<<<nb((long)BB*NPIX), TPB, 0, stream>>>(T1, tw, Dk);
    dgs_kernel<<<nb((long)NPIX), TPB, 0, stream>>>(filt, lam, tw, Dgs);
    pad_pack<<<nb((long)NP*NPIX), TPB, 0, stream>>>(y, R0, CA);

    const int FG = 920;   // 8 XCD groups x 115
    const float isc = 1.0f/(float)HH;
    fft_mfma<<<FG, TPB, 0, stream>>>(CA, CB, Btf, tw, 1.0f, 0);
    fft_mfma<<<FG, TPB, 0, stream>>>(CB, CA, Btf, tw, 1.0f, 0);
    for (int it = 0; it < 3; it++) {
        specmul<<<nb((long)NP*NPIX), TPB, 0, stream>>>(CA, Dk, Dgs, CB, 0);
        fft_mfma<<<FG, TPB, 0, stream>>>(CB, CA, Bti, tw, isc, 1);
        fft_mfma<<<FG, TPB, 0, stream>>>(CA, CB, Bti, tw, isc, 1);
        blend_kernel<<<nb((long)NP*NPIX), TPB, 0, stream>>>(CB, valp, R0, CA);
        fft_mfma<<<FG, TPB, 0, stream>>>(CA, CB, Btf, tw, 1.0f, 0);
        fft_mfma<<<FG, TPB, 0, stream>>>(CB, CA, Btf, tw, 1.0f, 0);
    }
    specmul<<<nb((long)NP*NPIX), TPB, 0, stream>>>(CA, Dk, Dgs, CB, 1);
    fft_mfma<<<FG, TPB, 0, stream>>>(CB, CA, Bti, tw, isc, 1);
    fft_mfma<<<FG, TPB, 0, stream>>>(CA, CB, Bti, tw, isc, 1);
    out_kernel<<<nb((long)NP*NPIX), TPB, 0, stream>>>(CB, out);
}